// Round 11
// baseline (256.882 us; speedup 1.0000x reference)
//
#include <hip/hip_runtime.h>
#include <hip/hip_bf16.h>

#define DIN   5120
#define LSEQ  2048
#define BATCH 2
#define MROWS 4096      // BATCH*LSEQ
#define EOUT  192       // DT_RANK + 2N
#define RDT   160       // DT_RANK
#define NST   16
#define NC    64        // scan chunks
#define LC    32        // timesteps per chunk (NC*LC == LSEQ)
#define LOG2E 1.44269504088896f
#define LN2   0.69314718055995f

typedef __attribute__((ext_vector_type(8))) short bf16x8;
typedef __attribute__((ext_vector_type(4))) float f32x4;

// ---------------- helpers ----------------
__device__ __forceinline__ void stdelta(float* p, size_t i, float v) { p[i] = v; }
__device__ __forceinline__ void stdelta(__hip_bfloat16* p, size_t i, float v) { p[i] = __float2bfloat16(v); }
__device__ __forceinline__ float lddelta(const float* p, size_t i) { return p[i]; }
__device__ __forceinline__ float lddelta(const __hip_bfloat16* p, size_t i) { return __bfloat162float(p[i]); }

// hw-trans softplus: ln(1+e^v) = max(v,0) + log2(1+2^(-|v|*log2e))*ln2
__device__ __forceinline__ float softplus_fast(float v) {
    float t = __builtin_amdgcn_exp2f(-fabsf(v) * LOG2E);
    return fmaxf(v, 0.f) + __builtin_amdgcn_logf(1.f + t) * LN2;
}
__device__ __forceinline__ unsigned short bf16rne(float f) {
    unsigned int u = __float_as_uint(f);
    unsigned int r = (u + 0x7FFFu + ((u >> 16) & 1u)) >> 16;
    return (unsigned short)r;
}
// 8 fp32 -> bf16 hi (RNE, HW cvt) + lo (RNE of residual)
__device__ __forceinline__ void cvt8(float4 a, float4 b, bf16x8& h, bf16x8& l) {
    float v[8] = {a.x, a.y, a.z, a.w, b.x, b.y, b.z, b.w};
    #pragma unroll
    for (int e = 0; e < 8; e++) {
        __hip_bfloat16 hb = __float2bfloat16(v[e]);
        float hf = __bfloat162float(hb);
        __hip_bfloat16 lb = __float2bfloat16(v[e] - hf);
        h[e] = *reinterpret_cast<const short*>(&hb);
        l[e] = *reinterpret_cast<const short*>(&lb);
    }
}

// ---------------- K0: fp32 -> bf16 (RNE) converter ----------------
__global__ void k0_cvtw(const float* __restrict__ w, ushort* __restrict__ bw) {
    int i = blockIdx.x * 256 + threadIdx.x;
    float4 v = reinterpret_cast<const float4*>(w)[i];
    ushort4 o = make_ushort4(bf16rne(v.x), bf16rne(v.y), bf16rne(v.z), bf16rne(v.w));
    reinterpret_cast<ushort4*>(bw)[i] = o;
}

// ---------------- K1 (MFMA, no LDS): x_dbl partials = x @ x_proj_w^T ----------------
// Block 64m x 192e, 4 waves each 16m. Grid (MROWS/64, 16) = 1024 blocks.
// Key fix vs r10: ALL 12 B-fragment loads batched into bb[12] (independent,
// in-flight together) -> L2 latency paid once per kk, not 12x.
template <int KPS>   // k-elements per split
__global__ __launch_bounds__(256) void k1_mfma(const float* __restrict__ x,
                                               const ushort* __restrict__ bWp,
                                               float* __restrict__ part) {
    const int tid = threadIdx.x;
    const int m_base = blockIdx.x * 64;
    const int k_base = blockIdx.y * KPS;
    const int lane = tid & 63, w = tid >> 6;
    const int lr = lane & 15, lg = lane >> 4;
    const int wm = m_base + w * 16;

    f32x4 acc[12];
    #pragma unroll
    for (int j = 0; j < 12; j++) acc[j] = (f32x4)(0.f);

    const float* xr = x + (size_t)(wm + lr) * DIN + k_base + lg * 8;
    const ushort* br = bWp + (size_t)lr * DIN + k_base + lg * 8;

    for (int kk = 0; kk < KPS / 32; kk++) {
        const int ko = kk * 32;
        // batch-issue all loads for this kk: 12 B frags + 2 x vectors
        bf16x8 bb[12];
        #pragma unroll
        for (int j = 0; j < 12; j++)
            bb[j] = *reinterpret_cast<const bf16x8*>(br + (size_t)j * 16 * DIN + ko);
        float4 v0 = *reinterpret_cast<const float4*>(xr + ko);
        float4 v1 = *reinterpret_cast<const float4*>(xr + ko + 4);
        bf16x8 ah, al;
        cvt8(v0, v1, ah, al);
        #pragma unroll
        for (int j = 0; j < 12; j++) {
            acc[j] = __builtin_amdgcn_mfma_f32_16x16x32_bf16(ah, bb[j], acc[j], 0, 0, 0);
            acc[j] = __builtin_amdgcn_mfma_f32_16x16x32_bf16(al, bb[j], acc[j], 0, 0, 0);
        }
    }
    float* p = part + (size_t)blockIdx.y * MROWS * EOUT;
    #pragma unroll
    for (int j = 0; j < 12; j++) {
        const int e = j * 16 + lr;
        const int m0 = wm + lg * 4;
        #pragma unroll
        for (int r = 0; r < 4; r++)
            p[(size_t)(m0 + r) * EOUT + e] = acc[j][r];
    }
}

// reduce split-K partials; emit xdbl fp32 + dtraw (cols<160) as bf16 hi/lo
template <int KS>
__global__ void k1_reduce(const float* __restrict__ part, float* __restrict__ xdbl,
                          ushort* __restrict__ aHi, ushort* __restrict__ aLo) {
    int i = blockIdx.x * 256 + threadIdx.x;   // float4 idx over [MROWS][48]
    const float4* p = reinterpret_cast<const float4*>(part);
    float4 s = p[i];
    #pragma unroll
    for (int k = 1; k < KS; k++) {
        float4 v = p[(size_t)k * (MROWS * EOUT / 4) + i];
        s.x += v.x; s.y += v.y; s.z += v.z; s.w += v.w;
    }
    reinterpret_cast<float4*>(xdbl)[i] = s;
    int row = i / 48, e4 = i % 48;
    if (e4 < 40) {
        unsigned int hx = __float_as_uint(s.x) & 0xFFFF0000u;
        unsigned int hy = __float_as_uint(s.y) & 0xFFFF0000u;
        unsigned int hz = __float_as_uint(s.z) & 0xFFFF0000u;
        unsigned int hw = __float_as_uint(s.w) & 0xFFFF0000u;
        ushort4 hv = make_ushort4((unsigned short)(hx >> 16), (unsigned short)(hy >> 16),
                                  (unsigned short)(hz >> 16), (unsigned short)(hw >> 16));
        ushort4 lv = make_ushort4(bf16rne(s.x - __uint_as_float(hx)),
                                  bf16rne(s.y - __uint_as_float(hy)),
                                  bf16rne(s.z - __uint_as_float(hz)),
                                  bf16rne(s.w - __uint_as_float(hw)));
        *reinterpret_cast<ushort4*>(&aHi[(size_t)row * RDT + e4 * 4]) = hv;
        *reinterpret_cast<ushort4*>(&aLo[(size_t)row * RDT + e4 * 4]) = lv;
    }
}

// ---------------- K2 (MFMA, no LDS): delta = softplus(dtraw @ w2^T + b) ----------------
template <typename DT>
__global__ __launch_bounds__(256, 3) void k2_mfma(const ushort* __restrict__ aHi,
                                                  const ushort* __restrict__ aLo,
                                                  const ushort* __restrict__ bW,
                                                  const float* __restrict__ bias,
                                                  DT* __restrict__ delta) {
    const int tid = threadIdx.x;
    const int m_base = blockIdx.x * 64, d_base = blockIdx.y * 256;
    const int lane = tid & 63, w = tid >> 6;
    const int wr = w >> 1, wc = w & 1;
    const int lr = lane & 15, lg = lane >> 4;

    f32x4 acc[2][8];
    #pragma unroll
    for (int i = 0; i < 2; i++)
        #pragma unroll
        for (int j = 0; j < 8; j++) acc[i][j] = (f32x4)(0.f);

    const size_t arow = (size_t)(m_base + wr * 32 + lr) * RDT;
    const size_t brow = (size_t)(d_base + wc * 128 + lr) * RDT;

    #pragma unroll
    for (int kk = 0; kk < 5; kk++) {
        const int ko = kk * 32 + lg * 8;
        bf16x8 ah0 = *reinterpret_cast<const bf16x8*>(aHi + arow + ko);
        bf16x8 ah1 = *reinterpret_cast<const bf16x8*>(aHi + arow + 16 * RDT + ko);
        bf16x8 al0 = *reinterpret_cast<const bf16x8*>(aLo + arow + ko);
        bf16x8 al1 = *reinterpret_cast<const bf16x8*>(aLo + arow + 16 * RDT + ko);
        #pragma unroll
        for (int j = 0; j < 8; j++) {
            bf16x8 bb = *reinterpret_cast<const bf16x8*>(bW + brow + (size_t)j * 16 * RDT + ko);
            acc[0][j] = __builtin_amdgcn_mfma_f32_16x16x32_bf16(ah0, bb, acc[0][j], 0, 0, 0);
            acc[1][j] = __builtin_amdgcn_mfma_f32_16x16x32_bf16(ah1, bb, acc[1][j], 0, 0, 0);
            acc[0][j] = __builtin_amdgcn_mfma_f32_16x16x32_bf16(al0, bb, acc[0][j], 0, 0, 0);
            acc[1][j] = __builtin_amdgcn_mfma_f32_16x16x32_bf16(al1, bb, acc[1][j], 0, 0, 0);
        }
    }

    #pragma unroll
    for (int j = 0; j < 8; j++) {
        const int gd = d_base + wc * 128 + j * 16 + lr;
        const float bv = bias[gd];
        #pragma unroll
        for (int i = 0; i < 2; i++) {
            const int gm0 = m_base + wr * 32 + i * 16 + lg * 4;
            #pragma unroll
            for (int r = 0; r < 4; r++) {
                float v = acc[i][j][r] + bv;
                stdelta(delta, (size_t)(gm0 + r) * DIN + gd, softplus_fast(v));
            }
        }
    }
}

// ---------------- K3a: per-chunk local scan (h from 0), emit hend -> hboth + S ----------------
template <typename DT>
__global__ __launch_bounds__(256) void k3a_local(const float* __restrict__ x,
                                                 const DT* __restrict__ delta,
                                                 const float* __restrict__ xdbl,
                                                 const float* __restrict__ A_log,
                                                 float* __restrict__ Sbuf,
                                                 float* __restrict__ hboth) {
    const int tid = threadIdx.x;
    const int d = blockIdx.x * 256 + tid;
    const int c = blockIdx.y, b = blockIdx.z;

    float4 aq[4];
    #pragma unroll
    for (int q = 0; q < 4; q++) aq[q] = *reinterpret_cast<const float4*>(&A_log[d * NST + q * 4]);
    const float* av = reinterpret_cast<const float*>(aq);
    float A2[NST];
    #pragma unroll
    for (int n = 0; n < NST; n++) A2[n] = -expf(av[n]) * LOG2E;

    float h[NST];
    #pragma unroll
    for (int n = 0; n < NST; n++) h[n] = 0.f;
    float S = 0.f;

    const size_t gbase = (size_t)b * LSEQ * DIN + (size_t)c * LC * DIN + d;
    const float* Bbase = xdbl + ((size_t)b * LSEQ + (size_t)c * LC) * EOUT + RDT;

    float dv = lddelta(delta, gbase);
    float xv = x[gbase];
    float4 bq[4];
    {
        const float4* Bp = reinterpret_cast<const float4*>(Bbase);
        bq[0] = Bp[0]; bq[1] = Bp[1]; bq[2] = Bp[2]; bq[3] = Bp[3];
    }
    for (int tt = 0; tt < LC; tt++) {
        const int ttn = (tt + 1 < LC) ? tt + 1 : tt;
        float dv_n = lddelta(delta, gbase + (size_t)ttn * DIN);
        float xv_n = x[gbase + (size_t)ttn * DIN];
        float4 bqn[4];
        {
            const float4* Bp = reinterpret_cast<const float4*>(Bbase + (size_t)ttn * EOUT);
            bqn[0] = Bp[0]; bqn[1] = Bp[1]; bqn[2] = Bp[2]; bqn[3] = Bp[3];
        }
        const float* Bv = reinterpret_cast<const float*>(bq);
        S += dv;
        const float dvx = dv * xv;
        #pragma unroll
        for (int n = 0; n < NST; n++)
            h[n] = fmaf(__builtin_amdgcn_exp2f(dv * A2[n]), h[n], dvx * Bv[n]);
        dv = dv_n; xv = xv_n;
        bq[0] = bqn[0]; bq[1] = bqn[1]; bq[2] = bqn[2]; bq[3] = bqn[3];
    }
    Sbuf[((size_t)b * NC + c) * DIN + d] = S;
    float* hp = hboth + (((size_t)b * NC + c) * DIN + d) * NST;
    #pragma unroll
    for (int q = 0; q < 4; q++)
        reinterpret_cast<float4*>(hp)[q] = make_float4(h[q*4], h[q*4+1], h[q*4+2], h[q*4+3]);
}

// ---------------- K3b: sequential chunk combine, IN-PLACE hend -> hinit ----------------
__global__ __launch_bounds__(256) void k3b_combine(const float* __restrict__ Sbuf,
                                                   float* __restrict__ hboth,
                                                   const float* __restrict__ A_log) {
    const int i = blockIdx.x * 256 + threadIdx.x;   // < BATCH*DIN*4
    const int b = i / (DIN * 4);
    const int r = i % (DIN * 4);
    const int d = r >> 2, q = r & 3;
    float4 av = *reinterpret_cast<const float4*>(&A_log[d * NST + q * 4]);
    float A2x = -expf(av.x) * LOG2E, A2y = -expf(av.y) * LOG2E;
    float A2z = -expf(av.z) * LOG2E, A2w = -expf(av.w) * LOG2E;
    float4 hi = make_float4(0.f, 0.f, 0.f, 0.f);
    float4* hb4 = reinterpret_cast<float4*>(hboth);
    for (int c = 0; c < NC; c++) {
        const size_t idx4 = (((size_t)b * NC + c) * DIN + d) * 4 + q;   // float4 units
        float4 he = hb4[idx4];      // read hend
        float S = Sbuf[((size_t)b * NC + c) * DIN + d];
        hb4[idx4] = hi;             // overwrite with hinit
        hi.x = fmaf(__builtin_amdgcn_exp2f(S * A2x), hi.x, he.x);
        hi.y = fmaf(__builtin_amdgcn_exp2f(S * A2y), hi.y, he.y);
        hi.z = fmaf(__builtin_amdgcn_exp2f(S * A2z), hi.z, he.z);
        hi.w = fmaf(__builtin_amdgcn_exp2f(S * A2w), hi.w, he.w);
    }
}

// ---------------- K3c: per-chunk scan from hinit (in hboth), emit y ----------------
template <typename DT>
__global__ __launch_bounds__(256) void k3c_scan(const float* __restrict__ x,
                                                const DT* __restrict__ delta,
                                                const float* __restrict__ xdbl,
                                                const float* __restrict__ A_log,
                                                const float* __restrict__ Dw,
                                                const float* __restrict__ hboth,
                                                float* __restrict__ out) {
    const int tid = threadIdx.x;
    const int d = blockIdx.x * 256 + tid;
    const int c = blockIdx.y, b = blockIdx.z;

    float4 aq[4];
    #pragma unroll
    for (int q = 0; q < 4; q++) aq[q] = *reinterpret_cast<const float4*>(&A_log[d * NST + q * 4]);
    const float* av = reinterpret_cast<const float*>(aq);
    float A2[NST];
    #pragma unroll
    for (int n = 0; n < NST; n++) A2[n] = -expf(av[n]) * LOG2E;

    float h[NST];
    {
        const float* hp = hboth + (((size_t)b * NC + c) * DIN + d) * NST;
        float4 hq[4];
        #pragma unroll
        for (int q = 0; q < 4; q++) hq[q] = reinterpret_cast<const float4*>(hp)[q];
        const float* hv = reinterpret_cast<const float*>(hq);
        #pragma unroll
        for (int n = 0; n < NST; n++) h[n] = hv[n];
    }
    const float Dv = Dw[d];

    const size_t gbase = (size_t)b * LSEQ * DIN + (size_t)c * LC * DIN + d;
    const float* Bbase = xdbl + ((size_t)b * LSEQ + (size_t)c * LC) * EOUT + RDT;

    float dv = lddelta(delta, gbase);
    float xv = x[gbase];
    float4 bq[4], cq[4];
    {
        const float4* Bp = reinterpret_cast<const float4*>(Bbase);
        bq[0] = Bp[0]; bq[1] = Bp[1]; bq[2] = Bp[2]; bq[3] = Bp[3];
        cq[0] = Bp[4]; cq[1] = Bp[5]; cq[2] = Bp[6]; cq[3] = Bp[7];
    }
    for (int tt = 0; tt < LC; tt++) {
        const int ttn = (tt + 1 < LC) ? tt + 1 : tt;
        float dv_n = lddelta(delta, gbase + (size_t)ttn * DIN);
        float xv_n = x[gbase + (size_t)ttn * DIN];
        float4 bqn[4], cqn[4];
        {
            const float4* Bp = reinterpret_cast<const float4*>(Bbase + (size_t)ttn * EOUT);
            bqn[0] = Bp[0]; bqn[1] = Bp[1]; bqn[2] = Bp[2]; bqn[3] = Bp[3];
            cqn[0] = Bp[4]; cqn[1] = Bp[5]; cqn[2] = Bp[6]; cqn[3] = Bp[7];
        }
        const float* Bv = reinterpret_cast<const float*>(bq);
        const float* Cv = reinterpret_cast<const float*>(cq);
        const float dvx = dv * xv;
        float y0 = 0.f, y1 = 0.f, y2 = 0.f, y3 = 0.f;
        #pragma unroll
        for (int n = 0; n < NST; n += 4) {
            h[n+0] = fmaf(__builtin_amdgcn_exp2f(dv * A2[n+0]), h[n+0], dvx * Bv[n+0]);
            y0 = fmaf(h[n+0], Cv[n+0], y0);
            h[n+1] = fmaf(__builtin_amdgcn_exp2f(dv * A2[n+1]), h[n+1], dvx * Bv[n+1]);
            y1 = fmaf(h[n+1], Cv[n+1], y1);
            h[n+2] = fmaf(__builtin_amdgcn_exp2f(dv * A2[n+2]), h[n+2], dvx * Bv[n+2]);
            y2 = fmaf(h[n+2], Cv[n+2], y2);
            h[n+3] = fmaf(__builtin_amdgcn_exp2f(dv * A2[n+3]), h[n+3], dvx * Bv[n+3]);
            y3 = fmaf(h[n+3], Cv[n+3], y3);
        }
        out[gbase + (size_t)tt * DIN] = ((y0 + y1) + (y2 + y3)) + xv * Dv;
        dv = dv_n; xv = xv_n;
        bq[0] = bqn[0]; bq[1] = bqn[1]; bq[2] = bqn[2]; bq[3] = bqn[3];
        cq[0] = cqn[0]; cq[1] = cqn[1]; cq[2] = cqn[2]; cq[3] = cqn[3];
    }
}

extern "C" void kernel_launch(void* const* d_in, const int* in_sizes, int n_in,
                              void* d_out, int out_size, void* d_ws, size_t ws_size,
                              hipStream_t stream) {
    const float* x     = (const float*)d_in[0];
    const float* A_log = (const float*)d_in[1];
    const float* Dw    = (const float*)d_in[2];
    const float* xpw   = (const float*)d_in[3];
    const float* dtw   = (const float*)d_in[4];
    const float* dtb   = (const float*)d_in[5];
    float* out = (float*)d_out;

    char* ws = (char*)d_ws;
    size_t off = 0;
    float* xdbl  = (float*)(ws + off); off += (size_t)MROWS * EOUT * 4;           // 3.15 MB
    float* hboth = (float*)(ws + off); off += (size_t)BATCH * NC * DIN * NST * 4; // 41.9 MB (hend->hinit in place)
    float* Sbuf  = (float*)(ws + off); off += (size_t)BATCH * NC * DIN * 4;       // 2.62 MB
    ushort* aHi  = (ushort*)(ws + off); off += (size_t)MROWS * RDT * 2;           // 1.31 MB
    ushort* aLo  = (ushort*)(ws + off); off += (size_t)MROWS * RDT * 2;           // 1.31 MB
    ushort* bW   = (ushort*)(ws + off); off += (size_t)DIN * RDT * 2;             // 1.64 MB
    ushort* bWp  = (ushort*)(ws + off); off += (size_t)EOUT * DIN * 2;            // 1.97 MB
    const size_t delta_off = off;                                                 // ~53.9 MB
    const bool f32ok = ws_size >= delta_off + (size_t)MROWS * DIN * 4;            // needs ~137.9 MB

    k0_cvtw<<<dim3(EOUT * DIN / 4 / 256), 256, 0, stream>>>(xpw, bWp);
    k0_cvtw<<<dim3(DIN * RDT / 4 / 256), 256, 0, stream>>>(dtw, bW);

    if (f32ok) {
        // split-K=16 partials (50.3 MB) alias the fp32 delta region (84 MB, dead until k2)
        float* part = (float*)(ws + delta_off);
        float* delta = (float*)(ws + delta_off);
        k1_mfma<DIN / 16><<<dim3(MROWS / 64, 16), 256, 0, stream>>>(x, bWp, part);
        k1_reduce<16><<<dim3(MROWS * EOUT / 4 / 256), 256, 0, stream>>>(part, xdbl, aHi, aLo);
        k2_mfma<float><<<dim3(MROWS / 64, DIN / 256), 256, 0, stream>>>(aHi, aLo, bW, dtb, delta);
        k3a_local<float><<<dim3(DIN / 256, NC, BATCH), 256, 0, stream>>>(x, delta, xdbl, A_log, Sbuf, hboth);
        k3b_combine<<<dim3(BATCH * DIN * 4 / 256), 256, 0, stream>>>(Sbuf, hboth, A_log);
        k3c_scan<float><<<dim3(DIN / 256, NC, BATCH), 256, 0, stream>>>(x, delta, xdbl, A_log, Dw, hboth, out);
    } else {
        // split-K=8 partials (25.2 MB) alias hboth (41.9 MB, dead until k3a)
        float* part = hboth;
        __hip_bfloat16* delta = (__hip_bfloat16*)(ws + delta_off);
        k1_mfma<DIN / 8><<<dim3(MROWS / 64, 8), 256, 0, stream>>>(x, bWp, part);
        k1_reduce<8><<<dim3(MROWS * EOUT / 4 / 256), 256, 0, stream>>>(part, xdbl, aHi, aLo);
        k2_mfma<__hip_bfloat16><<<dim3(MROWS / 64, DIN / 256), 256, 0, stream>>>(aHi, aLo, bW, dtb, delta);
        k3a_local<__hip_bfloat16><<<dim3(DIN / 256, NC, BATCH), 256, 0, stream>>>(x, delta, xdbl, A_log, Sbuf, hboth);
        k3b_combine<<<dim3(BATCH * DIN * 4 / 256), 256, 0, stream>>>(Sbuf, hboth, A_log);
        k3c_scan<__hip_bfloat16><<<dim3(DIN / 256, NC, BATCH), 256, 0, stream>>>(x, delta, xdbl, A_log, Dw, hboth, out);
    }
}

// Round 14
// 227.515 us; speedup vs baseline: 1.1291x; 1.1291x over previous
//
#include <hip/hip_runtime.h>
#include <hip/hip_bf16.h>

#define DIN   5120
#define LSEQ  2048
#define BATCH 2
#define MROWS 4096      // BATCH*LSEQ
#define EOUT  192       // DT_RANK + 2N
#define RDT   160       // DT_RANK
#define NST   16
#define NC    64        // scan chunks
#define LC    32        // timesteps per chunk (NC*LC == LSEQ)
#define LOG2E 1.44269504088896f
#define LN2   0.69314718055995f
#define KB1   (DIN / 32)   // 160 k-blocks in w1 (K = DIN)
#define KB2   (RDT / 32)   // 5 k-blocks in w2 (K = RDT)

typedef __attribute__((ext_vector_type(8))) short bf16x8;
typedef __attribute__((ext_vector_type(4))) float f32x4;

// ---------------- helpers ----------------
__device__ __forceinline__ void stdelta(float* p, size_t i, float v) { p[i] = v; }
__device__ __forceinline__ void stdelta(__hip_bfloat16* p, size_t i, float v) { p[i] = __float2bfloat16(v); }
__device__ __forceinline__ float lddelta(const float* p, size_t i) { return p[i]; }
__device__ __forceinline__ float lddelta(const __hip_bfloat16* p, size_t i) { return __bfloat162float(p[i]); }

// hw-trans softplus: ln(1+e^v) = max(v,0) + log2(1+2^(-|v|*log2e))*ln2
__device__ __forceinline__ float softplus_fast(float v) {
    float t = __builtin_amdgcn_exp2f(-fabsf(v) * LOG2E);
    return fmaxf(v, 0.f) + __builtin_amdgcn_logf(1.f + t) * LN2;
}
__device__ __forceinline__ unsigned short bf16rne(float f) {
    unsigned int u = __float_as_uint(f);
    unsigned int r = (u + 0x7FFFu + ((u >> 16) & 1u)) >> 16;
    return (unsigned short)r;
}
// 8 fp32 -> bf16 hi (RNE, HW cvt) + lo (RNE of residual)
__device__ __forceinline__ void cvt8(float4 a, float4 b, bf16x8& h, bf16x8& l) {
    float v[8] = {a.x, a.y, a.z, a.w, b.x, b.y, b.z, b.w};
    #pragma unroll
    for (int e = 0; e < 8; e++) {
        __hip_bfloat16 hb = __float2bfloat16(v[e]);
        float hf = __bfloat162float(hb);
        __hip_bfloat16 lb = __float2bfloat16(v[e] - hf);
        h[e] = *reinterpret_cast<const short*>(&hb);
        l[e] = *reinterpret_cast<const short*>(&lb);
    }
}

// ---------------- K0: pack fp32 weight [ROWS][K] -> bf16 MFMA-fragment order ----------
// piece p = ((j*KB + kkg)*4 + lg)*16 + lr  holds row j*16+lr, k = kkg*32+lg*8 .. +8.
// A wave's fragment load (fixed j,kkg; lanes lg*16+lr) is then 64x16B contiguous.
template <int K>
__global__ void k0_packB(const float* __restrict__ w, ushort* __restrict__ bP) {
    const int KBl = K / 32;
    int p = blockIdx.x * 256 + threadIdx.x;          // piece index (ROWS*K/8 total)
    int lr = p & 15, lg = (p >> 4) & 3;
    int kkg = (p >> 6) % KBl, j = p / (64 * KBl);
    const float* src = w + (size_t)(j * 16 + lr) * K + kkg * 32 + lg * 8;
    float4 a = *reinterpret_cast<const float4*>(src);
    float4 b = *reinterpret_cast<const float4*>(src + 4);
    ushort o[8] = {bf16rne(a.x), bf16rne(a.y), bf16rne(a.z), bf16rne(a.w),
                   bf16rne(b.x), bf16rne(b.y), bf16rne(b.z), bf16rne(b.w)};
    ushort* dst = bP + (size_t)p * 8;
    *reinterpret_cast<ushort4*>(dst)     = make_ushort4(o[0], o[1], o[2], o[3]);
    *reinterpret_cast<ushort4*>(dst + 4) = make_ushort4(o[4], o[5], o[6], o[7]);
}

// ---------------- K1 (MFMA, LDS-staged x + packed B): x_dbl partials ----------------
// Block 64m x 192e; 4 waves each 16m x 192e. x staged in double-buffered LDS
// (coalesced global reads, XOR-swizzled to kill bank conflicts); B fragments
// from packed-global (1KB coalesced, L2-hot). Split-K grid (MROWS/64, KSPLIT).
#define K1_BK 64
template <int KPS>   // k-elements per split
__global__ __launch_bounds__(256) void k1_mfma(const float* __restrict__ x,
                                               const ushort* __restrict__ bP,
                                               float* __restrict__ part) {
    __shared__ float xs[2][64 * 64];   // 32 KB, [buf][row*64 + swz(col16)*4]
    const int tid = threadIdx.x;
    const int m_base = blockIdx.x * 64;
    const int k_base = blockIdx.y * KPS;
    const int lane = tid & 63, w = tid >> 6;
    const int lr = lane & 15, lg = lane >> 4;
    const int wm = w * 16;             // wave's row offset in block tile

    f32x4 acc[12];
    #pragma unroll
    for (int j = 0; j < 12; j++) acc[j] = (f32x4)(0.f);

    const int srow4 = tid >> 4, scol = tid & 15;   // staging: 16 rows/pass x 16 cols

    auto stage = [&](int buf, int kc) {
        #pragma unroll
        for (int p = 0; p < 4; p++) {
            int row = p * 16 + srow4;
            float4 v = *reinterpret_cast<const float4*>(
                &x[(size_t)(m_base + row) * DIN + k_base + kc + scol * 4]);
            *reinterpret_cast<float4*>(&xs[buf][row * 64 + ((scol ^ (row & 7)) * 4)]) = v;
        }
    };

    stage(0, 0);
    const ushort* bpl = bP + ((size_t)lg * 16 + lr) * 8;   // lane base in packed B
    __syncthreads();

    int buf = 0;
    for (int kc = 0; kc < KPS; kc += K1_BK) {
        if (kc + K1_BK < KPS) stage(buf ^ 1, kc + K1_BK);
        #pragma unroll
        for (int kk = 0; kk < K1_BK / 32; kk++) {
            const int kglob = (k_base + kc) / 32 + kk;     // global k-block
            bf16x8 bb[12];
            #pragma unroll
            for (int j = 0; j < 12; j++)
                bb[j] = *reinterpret_cast<const bf16x8*>(bpl + ((size_t)j * KB1 + kglob) * 512);
            const int row = wm + lr;
            const int ca = kk * 8 + lg * 2;                // 16B-col index in tile
            float4 f0 = *reinterpret_cast<const float4*>(&xs[buf][row * 64 + ((ca ^ (row & 7)) * 4)]);
            float4 f1 = *reinterpret_cast<const float4*>(&xs[buf][row * 64 + (((ca + 1) ^ (row & 7)) * 4)]);
            bf16x8 ah, al;
            cvt8(f0, f1, ah, al);
            #pragma unroll
            for (int j = 0; j < 12; j++) {
                acc[j] = __builtin_amdgcn_mfma_f32_16x16x32_bf16(ah, bb[j], acc[j], 0, 0, 0);
                acc[j] = __builtin_amdgcn_mfma_f32_16x16x32_bf16(al, bb[j], acc[j], 0, 0, 0);
            }
        }
        __syncthreads();
        buf ^= 1;
    }
    float* p = part + (size_t)blockIdx.y * MROWS * EOUT;
    #pragma unroll
    for (int j = 0; j < 12; j++) {
        const int e = j * 16 + lr;
        const int m0 = wm + lg * 4;
        #pragma unroll
        for (int r = 0; r < 4; r++)
            p[(size_t)(m_base + m0 + r) * EOUT + e] = acc[j][r];
    }
}

// reduce split-K partials; emit xdbl fp32 + dtraw (cols<160) as bf16 hi/lo
template <int KS>
__global__ void k1_reduce(const float* __restrict__ part, float* __restrict__ xdbl,
                          ushort* __restrict__ aHi, ushort* __restrict__ aLo) {
    int i = blockIdx.x * 256 + threadIdx.x;   // float4 idx over [MROWS][48]
    const float4* p = reinterpret_cast<const float4*>(part);
    float4 s = p[i];
    #pragma unroll
    for (int k = 1; k < KS; k++) {
        float4 v = p[(size_t)k * (MROWS * EOUT / 4) + i];
        s.x += v.x; s.y += v.y; s.z += v.z; s.w += v.w;
    }
    reinterpret_cast<float4*>(xdbl)[i] = s;
    int row = i / 48, e4 = i % 48;
    if (e4 < 40) {
        unsigned int hx = __float_as_uint(s.x) & 0xFFFF0000u;
        unsigned int hy = __float_as_uint(s.y) & 0xFFFF0000u;
        unsigned int hz = __float_as_uint(s.z) & 0xFFFF0000u;
        unsigned int hw = __float_as_uint(s.w) & 0xFFFF0000u;
        ushort4 hv = make_ushort4((unsigned short)(hx >> 16), (unsigned short)(hy >> 16),
                                  (unsigned short)(hz >> 16), (unsigned short)(hw >> 16));
        ushort4 lv = make_ushort4(bf16rne(s.x - __uint_as_float(hx)),
                                  bf16rne(s.y - __uint_as_float(hy)),
                                  bf16rne(s.z - __uint_as_float(hz)),
                                  bf16rne(s.w - __uint_as_float(hw)));
        *reinterpret_cast<ushort4*>(&aHi[(size_t)row * RDT + e4 * 4]) = hv;
        *reinterpret_cast<ushort4*>(&aLo[(size_t)row * RDT + e4 * 4]) = lv;
    }
}

// ---------------- K2 (MFMA, packed B): delta = softplus(dtraw @ w2^T + b) -----------
template <typename DT>
__global__ __launch_bounds__(256, 3) void k2_mfma(const ushort* __restrict__ aHi,
                                                  const ushort* __restrict__ aLo,
                                                  const ushort* __restrict__ bP2,
                                                  const float* __restrict__ bias,
                                                  DT* __restrict__ delta) {
    const int tid = threadIdx.x;
    const int m_base = blockIdx.x * 64, d_base = blockIdx.y * 256;
    const int lane = tid & 63, w = tid >> 6;
    const int wr = w >> 1, wc = w & 1;
    const int lr = lane & 15, lg = lane >> 4;

    f32x4 acc[2][8];
    #pragma unroll
    for (int i = 0; i < 2; i++)
        #pragma unroll
        for (int j = 0; j < 8; j++) acc[i][j] = (f32x4)(0.f);

    const size_t arow = (size_t)(m_base + wr * 32 + lr) * RDT;
    const int jt_base = d_base / 16 + wc * 8;          // B j-tile base
    const ushort* bpl = bP2 + ((size_t)lg * 16 + lr) * 8;

    #pragma unroll
    for (int kk = 0; kk < 5; kk++) {
        const int ko = kk * 32 + lg * 8;
        bf16x8 ah0 = *reinterpret_cast<const bf16x8*>(aHi + arow + ko);
        bf16x8 ah1 = *reinterpret_cast<const bf16x8*>(aHi + arow + 16 * RDT + ko);
        bf16x8 al0 = *reinterpret_cast<const bf16x8*>(aLo + arow + ko);
        bf16x8 al1 = *reinterpret_cast<const bf16x8*>(aLo + arow + 16 * RDT + ko);
        bf16x8 bb[8];
        #pragma unroll
        for (int j = 0; j < 8; j++)
            bb[j] = *reinterpret_cast<const bf16x8*>(bpl + ((size_t)(jt_base + j) * KB2 + kk) * 512);
        #pragma unroll
        for (int j = 0; j < 8; j++) {
            acc[0][j] = __builtin_amdgcn_mfma_f32_16x16x32_bf16(ah0, bb[j], acc[0][j], 0, 0, 0);
            acc[1][j] = __builtin_amdgcn_mfma_f32_16x16x32_bf16(ah1, bb[j], acc[1][j], 0, 0, 0);
            acc[0][j] = __builtin_amdgcn_mfma_f32_16x16x32_bf16(al0, bb[j], acc[0][j], 0, 0, 0);
            acc[1][j] = __builtin_amdgcn_mfma_f32_16x16x32_bf16(al1, bb[j], acc[1][j], 0, 0, 0);
        }
    }

    #pragma unroll
    for (int j = 0; j < 8; j++) {
        const int gd = d_base + wc * 128 + j * 16 + lr;
        const float bv = bias[gd];
        #pragma unroll
        for (int i = 0; i < 2; i++) {
            const int gm0 = m_base + wr * 32 + i * 16 + lg * 4;
            #pragma unroll
            for (int r = 0; r < 4; r++) {
                float v = acc[i][j][r] + bv;
                stdelta(delta, (size_t)(gm0 + r) * DIN + gd, softplus_fast(v));
            }
        }
    }
}

// ---------------- K3a: per-chunk local scan (h from 0), emit hend -> hboth + S ----------------
template <typename DT>
__global__ __launch_bounds__(256) void k3a_local(const float* __restrict__ x,
                                                 const DT* __restrict__ delta,
                                                 const float* __restrict__ xdbl,
                                                 const float* __restrict__ A_log,
                                                 float* __restrict__ Sbuf,
                                                 float* __restrict__ hboth) {
    const int tid = threadIdx.x;
    const int d = blockIdx.x * 256 + tid;
    const int c = blockIdx.y, b = blockIdx.z;

    float4 aq[4];
    #pragma unroll
    for (int q = 0; q < 4; q++) aq[q] = *reinterpret_cast<const float4*>(&A_log[d * NST + q * 4]);
    const float* av = reinterpret_cast<const float*>(aq);
    float A2[NST];
    #pragma unroll
    for (int n = 0; n < NST; n++) A2[n] = -expf(av[n]) * LOG2E;

    float h[NST];
    #pragma unroll
    for (int n = 0; n < NST; n++) h[n] = 0.f;
    float S = 0.f;

    const size_t gbase = (size_t)b * LSEQ * DIN + (size_t)c * LC * DIN + d;
    const float* Bbase = xdbl + ((size_t)b * LSEQ + (size_t)c * LC) * EOUT + RDT;

    float dv = lddelta(delta, gbase);
    float xv = x[gbase];
    float4 bq[4];
    {
        const float4* Bp = reinterpret_cast<const float4*>(Bbase);
        bq[0] = Bp[0]; bq[1] = Bp[1]; bq[2] = Bp[2]; bq[3] = Bp[3];
    }
    for (int tt = 0; tt < LC; tt++) {
        const int ttn = (tt + 1 < LC) ? tt + 1 : tt;
        float dv_n = lddelta(delta, gbase + (size_t)ttn * DIN);
        float xv_n = x[gbase + (size_t)ttn * DIN];
        float4 bqn[4];
        {
            const float4* Bp = reinterpret_cast<const float4*>(Bbase + (size_t)ttn * EOUT);
            bqn[0] = Bp[0]; bqn[1] = Bp[1]; bqn[2] = Bp[2]; bqn[3] = Bp[3];
        }
        const float* Bv = reinterpret_cast<const float*>(bq);
        S += dv;
        const float dvx = dv * xv;
        #pragma unroll
        for (int n = 0; n < NST; n++)
            h[n] = fmaf(__builtin_amdgcn_exp2f(dv * A2[n]), h[n], dvx * Bv[n]);
        dv = dv_n; xv = xv_n;
        bq[0] = bqn[0]; bq[1] = bqn[1]; bq[2] = bqn[2]; bq[3] = bqn[3];
    }
    Sbuf[((size_t)b * NC + c) * DIN + d] = S;
    float* hp = hboth + (((size_t)b * NC + c) * DIN + d) * NST;
    #pragma unroll
    for (int q = 0; q < 4; q++)
        reinterpret_cast<float4*>(hp)[q] = make_float4(h[q*4], h[q*4+1], h[q*4+2], h[q*4+3]);
}

// ---------------- K3b: sequential chunk combine, IN-PLACE hend -> hinit ----------------
__global__ __launch_bounds__(256) void k3b_combine(const float* __restrict__ Sbuf,
                                                   float* __restrict__ hboth,
                                                   const float* __restrict__ A_log) {
    const int i = blockIdx.x * 256 + threadIdx.x;   // < BATCH*DIN*4
    const int b = i / (DIN * 4);
    const int r = i % (DIN * 4);
    const int d = r >> 2, q = r & 3;
    float4 av = *reinterpret_cast<const float4*>(&A_log[d * NST + q * 4]);
    float A2x = -expf(av.x) * LOG2E, A2y = -expf(av.y) * LOG2E;
    float A2z = -expf(av.z) * LOG2E, A2w = -expf(av.w) * LOG2E;
    float4 hi = make_float4(0.f, 0.f, 0.f, 0.f);
    float4* hb4 = reinterpret_cast<float4*>(hboth);
    for (int c = 0; c < NC; c++) {
        const size_t idx4 = (((size_t)b * NC + c) * DIN + d) * 4 + q;   // float4 units
        float4 he = hb4[idx4];      // read hend
        float S = Sbuf[((size_t)b * NC + c) * DIN + d];
        hb4[idx4] = hi;             // overwrite with hinit
        hi.x = fmaf(__builtin_amdgcn_exp2f(S * A2x), hi.x, he.x);
        hi.y = fmaf(__builtin_amdgcn_exp2f(S * A2y), hi.y, he.y);
        hi.z = fmaf(__builtin_amdgcn_exp2f(S * A2z), hi.z, he.z);
        hi.w = fmaf(__builtin_amdgcn_exp2f(S * A2w), hi.w, he.w);
    }
}

// ---------------- K3c: per-chunk scan from hinit (in hboth), emit y ----------------
template <typename DT>
__global__ __launch_bounds__(256) void k3c_scan(const float* __restrict__ x,
                                                const DT* __restrict__ delta,
                                                const float* __restrict__ xdbl,
                                                const float* __restrict__ A_log,
                                                const float* __restrict__ Dw,
                                                const float* __restrict__ hboth,
                                                float* __restrict__ out) {
    const int tid = threadIdx.x;
    const int d = blockIdx.x * 256 + tid;
    const int c = blockIdx.y, b = blockIdx.z;

    float4 aq[4];
    #pragma unroll
    for (int q = 0; q < 4; q++) aq[q] = *reinterpret_cast<const float4*>(&A_log[d * NST + q * 4]);
    const float* av = reinterpret_cast<const float*>(aq);
    float A2[NST];
    #pragma unroll
    for (int n = 0; n < NST; n++) A2[n] = -expf(av[n]) * LOG2E;

    float h[NST];
    {
        const float* hp = hboth + (((size_t)b * NC + c) * DIN + d) * NST;
        float4 hq[4];
        #pragma unroll
        for (int q = 0; q < 4; q++) hq[q] = reinterpret_cast<const float4*>(hp)[q];
        const float* hv = reinterpret_cast<const float*>(hq);
        #pragma unroll
        for (int n = 0; n < NST; n++) h[n] = hv[n];
    }
    const float Dv = Dw[d];

    const size_t gbase = (size_t)b * LSEQ * DIN + (size_t)c * LC * DIN + d;
    const float* Bbase = xdbl + ((size_t)b * LSEQ + (size_t)c * LC) * EOUT + RDT;

    float dv = lddelta(delta, gbase);
    float xv = x[gbase];
    float4 bq[4], cq[4];
    {
        const float4* Bp = reinterpret_cast<const float4*>(Bbase);
        bq[0] = Bp[0]; bq[1] = Bp[1]; bq[2] = Bp[2]; bq[3] = Bp[3];
        cq[0] = Bp[4]; cq[1] = Bp[5]; cq[2] = Bp[6]; cq[3] = Bp[7];
    }
    for (int tt = 0; tt < LC; tt++) {
        const int ttn = (tt + 1 < LC) ? tt + 1 : tt;
        float dv_n = lddelta(delta, gbase + (size_t)ttn * DIN);
        float xv_n = x[gbase + (size_t)ttn * DIN];
        float4 bqn[4], cqn[4];
        {
            const float4* Bp = reinterpret_cast<const float4*>(Bbase + (size_t)ttn * EOUT);
            bqn[0] = Bp[0]; bqn[1] = Bp[1]; bqn[2] = Bp[2]; bqn[3] = Bp[3];
            cqn[0] = Bp[4]; cqn[1] = Bp[5]; cqn[2] = Bp[6]; cqn[3] = Bp[7];
        }
        const float* Bv = reinterpret_cast<const float*>(bq);
        const float* Cv = reinterpret_cast<const float*>(cq);
        const float dvx = dv * xv;
        float y0 = 0.f, y1 = 0.f, y2 = 0.f, y3 = 0.f;
        #pragma unroll
        for (int n = 0; n < NST; n += 4) {
            h[n+0] = fmaf(__builtin_amdgcn_exp2f(dv * A2[n+0]), h[n+0], dvx * Bv[n+0]);
            y0 = fmaf(h[n+0], Cv[n+0], y0);
            h[n+1] = fmaf(__builtin_amdgcn_exp2f(dv * A2[n+1]), h[n+1], dvx * Bv[n+1]);
            y1 = fmaf(h[n+1], Cv[n+1], y1);
            h[n+2] = fmaf(__builtin_amdgcn_exp2f(dv * A2[n+2]), h[n+2], dvx * Bv[n+2]);
            y2 = fmaf(h[n+2], Cv[n+2], y2);
            h[n+3] = fmaf(__builtin_amdgcn_exp2f(dv * A2[n+3]), h[n+3], dvx * Bv[n+3]);
            y3 = fmaf(h[n+3], Cv[n+3], y3);
        }
        out[gbase + (size_t)tt * DIN] = ((y0 + y1) + (y2 + y3)) + xv * Dv;
        dv = dv_n; xv = xv_n;
        bq[0] = bqn[0]; bq[1] = bqn[1]; bq[2] = bqn[2]; bq[3] = bqn[3];
        cq[0] = cqn[0]; cq[1] = cqn[1]; cq[2] = cqn[2]; cq[3] = cqn[3];
    }
}

extern "C" void kernel_launch(void* const* d_in, const int* in_sizes, int n_in,
                              void* d_out, int out_size, void* d_ws, size_t ws_size,
                              hipStream_t stream) {
    const float* x     = (const float*)d_in[0];
    const float* A_log = (const float*)d_in[1];
    const float* Dw    = (const float*)d_in[2];
    const float* xpw   = (const float*)d_in[3];
    const float* dtw   = (const float*)d_in[4];
    const float* dtb   = (const float*)d_in[5];
    float* out = (float*)d_out;

    char* ws = (char*)d_ws;
    size_t off = 0;
    float* xdbl  = (float*)(ws + off); off += (size_t)MROWS * EOUT * 4;           // 3.15 MB
    float* hboth = (float*)(ws + off); off += (size_t)BATCH * NC * DIN * NST * 4; // 41.9 MB
    float* Sbuf  = (float*)(ws + off); off += (size_t)BATCH * NC * DIN * 4;       // 2.62 MB
    ushort* aHi  = (ushort*)(ws + off); off += (size_t)MROWS * RDT * 2;           // 1.31 MB
    ushort* aLo  = (ushort*)(ws + off); off += (size_t)MROWS * RDT * 2;           // 1.31 MB
    ushort* bP2  = (ushort*)(ws + off); off += (size_t)DIN * RDT * 2;             // 1.64 MB (packed w2)
    ushort* bP1  = (ushort*)(ws + off); off += (size_t)EOUT * DIN * 2;            // 1.97 MB (packed xpw)
    const size_t delta_off = off;                                                 // ~53.9 MB
    const bool f32ok = ws_size >= delta_off + (size_t)MROWS * DIN * 4;            // needs ~137.9 MB

    k0_packB<DIN><<<dim3(EOUT * DIN / 8 / 256), 256, 0, stream>>>(xpw, bP1);
    k0_packB<RDT><<<dim3(DIN * RDT / 8 / 256), 256, 0, stream>>>(dtw, bP2);

    if (f32ok) {
        // split-K=16 partials (50.3 MB) alias the fp32 delta region (84 MB, dead until k2)
        float* part = (float*)(ws + delta_off);
        float* delta = (float*)(ws + delta_off);
        k1_mfma<DIN / 16><<<dim3(MROWS / 64, 16), 256, 0, stream>>>(x, bP1, part);
        k1_reduce<16><<<dim3(MROWS * EOUT / 4 / 256), 256, 0, stream>>>(part, xdbl, aHi, aLo);
        k2_mfma<float><<<dim3(MROWS / 64, DIN / 256), 256, 0, stream>>>(aHi, aLo, bP2, dtb, delta);
        k3a_local<float><<<dim3(DIN / 256, NC, BATCH), 256, 0, stream>>>(x, delta, xdbl, A_log, Sbuf, hboth);
        k3b_combine<<<dim3(BATCH * DIN * 4 / 256), 256, 0, stream>>>(Sbuf, hboth, A_log);
        k3c_scan<float><<<dim3(DIN / 256, NC, BATCH), 256, 0, stream>>>(x, delta, xdbl, A_log, Dw, hboth, out);
    } else {
        // split-K=8 partials (25.2 MB) alias hboth (41.9 MB, dead until k3a)
        float* part = hboth;
        __hip_bfloat16* delta = (__hip_bfloat16*)(ws + delta_off);
        k1_mfma<DIN / 8><<<dim3(MROWS / 64, 8), 256, 0, stream>>>(x, bP1, part);
        k1_reduce<8><<<dim3(MROWS * EOUT / 4 / 256), 256, 0, stream>>>(part, xdbl, aHi, aLo);
        k2_mfma<__hip_bfloat16><<<dim3(MROWS / 64, DIN / 256), 256, 0, stream>>>(aHi, aLo, bP2, dtb, delta);
        k3a_local<__hip_bfloat16><<<dim3(DIN / 256, NC, BATCH), 256, 0, stream>>>(x, delta, xdbl, A_log, Sbuf, hboth);
        k3b_combine<<<dim3(BATCH * DIN * 4 / 256), 256, 0, stream>>>(Sbuf, hboth, A_log);
        k3c_scan<__hip_bfloat16><<<dim3(DIN / 256, NC, BATCH), 256, 0, stream>>>(x, delta, xdbl, A_log, Dw, hboth, out);
    }
}